// Round 1
// baseline (97925.323 us; speedup 1.0000x reference)
//
#include <hip/hip_runtime.h>
#include <math.h>

// QLSTM persistent-kernel baseline (round 1).
// SEQ sequential steps, one device-wide software barrier per step.
// 256 blocks x 256 threads: block bb owns hidden units {2*bb, 2*bb+1} for all
// 4 gates (8 weight rows x 1024 cols, f32, resident in LDS = 32 KB).
// Per step: stage comb=[x_t | h_{t-1}] into LDS in 128-k chunks, f32 VALU dot
// products, gate nonlinearities, c in registers, h double-buffered in ws.

#define SEQ   2048
#define BATCH 64
#define DIN   512
#define HID   512
#define KTOT  (DIN + HID)   // 1024
#define NBLK  256
#define NTHR  256
#define CHUNK 128
#define NCHUNK (KTOT / CHUNK)  // 8
#define CPAD  65               // pad leading dim: conflict-free comb reads

__device__ __forceinline__ float sigmoidf_(float x) {
    return 1.0f / (1.0f + expf(-x));
}

__launch_bounds__(NTHR, 1)
__global__ void qlstm_persist(
    const float* __restrict__ x,                       // [SEQ][BATCH][DIN]
    const float* __restrict__ Wf, const float* __restrict__ bf,
    const float* __restrict__ Wi, const float* __restrict__ bi,
    const float* __restrict__ Wg, const float* __restrict__ bg,
    const float* __restrict__ Wo, const float* __restrict__ bo,
    float* __restrict__ out,                           // [SEQ][BATCH][HID] ++ hx ++ cx
    unsigned* __restrict__ bar,                        // zeroed by memset
    float* __restrict__ hbuf)                          // [2][BATCH][HID], zeroed
{
    __shared__ float Wl[8 * KTOT];          // 32 KB: rows r = gate*2 + jj (f,i,g,o)
    __shared__ float comb[CHUNK * CPAD];    // 33.25 KB
    __shared__ float gl[8 * BATCH];         // gate pre-activations exchange
    __shared__ float bias_l[8];

    const int tid = threadIdx.x;
    const int j0  = blockIdx.x * 2;

    // ---- one-time: load this block's 8 weight rows + biases into LDS ----
    {
        const float* wsrcs[4] = { Wf, Wi, Wg, Wo };
        const float* bsrcs[4] = { bf, bi, bg, bo };
        #pragma unroll
        for (int g = 0; g < 4; ++g) {
            const float* ws0 = wsrcs[g] + (size_t)(j0 + 0) * KTOT;
            const float* ws1 = wsrcs[g] + (size_t)(j0 + 1) * KTOT;
            for (int i = tid; i < KTOT; i += NTHR) {
                Wl[(g * 2 + 0) * KTOT + i] = ws0[i];
                Wl[(g * 2 + 1) * KTOT + i] = ws1[i];
            }
            if (tid == 0) {
                bias_l[g * 2 + 0] = bsrcs[g][j0 + 0];
                bias_l[g * 2 + 1] = bsrcs[g][j0 + 1];
            }
        }
    }
    __syncthreads();

    const int b = tid & 63;     // batch lane
    const int r = tid >> 6;     // 0..3 -> computes weight rows r and r+4
    float c_reg  = 0.0f;        // valid for tid < 128 (b, jj=tid>>6)
    float h_last = 0.0f;

    for (int t = 0; t < SEQ; ++t) {
        const int cur = t & 1;
        float acc0 = bias_l[r];
        float acc1 = bias_l[r + 4];

        #pragma unroll 1
        for (int kc = 0; kc < NCHUNK; ++kc) {
            __syncthreads();   // protect comb from previous chunk's readers
            // stage chunk: kc<4 -> x_t columns, kc>=4 -> h_{t-1} columns
            const float* src = (kc < NCHUNK / 2)
                ? (x    + (size_t)t   * (BATCH * DIN) + kc * CHUNK)
                : (hbuf + (size_t)cur * (BATCH * HID) + (kc - NCHUNK / 2) * CHUNK);
            #pragma unroll
            for (int it = 0; it < (CHUNK * BATCH) / (4 * NTHR); ++it) {  // 8
                int m  = it * NTHR + tid;        // 0..2047
                int q  = m & 31;                 // float4 index within row
                int bs = m >> 5;                 // batch
                float4 v = *(const float4*)(src + (size_t)bs * 512 + q * 4);
                int k = q * 4;
                comb[(k + 0) * CPAD + bs] = v.x;
                comb[(k + 1) * CPAD + bs] = v.y;
                comb[(k + 2) * CPAD + bs] = v.z;
                comb[(k + 3) * CPAD + bs] = v.w;
            }
            __syncthreads();
            const float* w0p = &Wl[(r    ) * KTOT + kc * CHUNK];
            const float* w1p = &Wl[(r + 4) * KTOT + kc * CHUNK];
            #pragma unroll 8
            for (int k = 0; k < CHUNK; ++k) {
                float cv = comb[k * CPAD + b];   // banks (k+b)%32: 2-way = free
                acc0 = fmaf(cv, w0p[k], acc0);
                acc1 = fmaf(cv, w1p[k], acc1);
            }
        }

        // exchange pre-activations; rows: f=jj, i=2+jj, g=4+jj, o=6+jj
        gl[(r    ) * BATCH + b] = acc0;
        gl[(r + 4) * BATCH + b] = acc1;
        __syncthreads();

        if (tid < 2 * BATCH) {
            const int eb = tid & 63;
            const int jj = tid >> 6;
            float fv = sigmoidf_(gl[(0 + jj) * BATCH + eb]);
            float iv = sigmoidf_(gl[(2 + jj) * BATCH + eb]);
            float gv = tanhf    (gl[(4 + jj) * BATCH + eb]);
            float ov = sigmoidf_(gl[(6 + jj) * BATCH + eb]);
            c_reg  = fv * c_reg + iv * gv;
            h_last = ov * tanhf(c_reg);
            out [(size_t)t * (BATCH * HID) + (size_t)eb * HID + (j0 + jj)] = h_last;
            hbuf[(size_t)(1 - cur) * (BATCH * HID) + (size_t)eb * HID + (j0 + jj)] = h_last;
        }

        // ---- device-wide barrier (skip after last step) ----
        if (t < SEQ - 1) {
            __syncthreads();   // all lanes' h stores executed before release
            if (tid == 0) {
                __hip_atomic_fetch_add(bar, 1u, __ATOMIC_RELEASE,
                                       __HIP_MEMORY_SCOPE_AGENT);
                const unsigned target = (unsigned)(t + 1) * NBLK;
                while (__hip_atomic_load(bar, __ATOMIC_ACQUIRE,
                                         __HIP_MEMORY_SCOPE_AGENT) < target)
                    __builtin_amdgcn_s_sleep(2);
            }
            __syncthreads();
        }
    }

    // final hx, cx
    if (tid < 2 * BATCH) {
        const int eb = tid & 63;
        const int jj = tid >> 6;
        const size_t obase = (size_t)SEQ * BATCH * HID;
        out[obase +              (size_t)eb * HID + (j0 + jj)] = h_last;
        out[obase + BATCH * HID + (size_t)eb * HID + (j0 + jj)] = c_reg;
    }
}

extern "C" void kernel_launch(void* const* d_in, const int* in_sizes, int n_in,
                              void* d_out, int out_size, void* d_ws, size_t ws_size,
                              hipStream_t stream) {
    const float* x  = (const float*)d_in[0];
    const float* Wf = (const float*)d_in[1];
    const float* bf = (const float*)d_in[2];
    const float* Wi = (const float*)d_in[3];
    const float* bi = (const float*)d_in[4];
    const float* Wg = (const float*)d_in[5];
    const float* bg = (const float*)d_in[6];
    const float* Wo = (const float*)d_in[7];
    const float* bo = (const float*)d_in[8];
    float* out = (float*)d_out;

    unsigned* bar = (unsigned*)d_ws;
    float* hbuf   = (float*)((char*)d_ws + 1024);

    // zero barrier counter + h double buffer (ws is poisoned 0xAA each call)
    hipMemsetAsync(d_ws, 0, 1024 + 2 * BATCH * HID * sizeof(float), stream);

    qlstm_persist<<<NBLK, NTHR, 0, stream>>>(
        x, Wf, bf, Wi, bi, Wg, bg, Wo, bo, out, bar, hbuf);
}